// Round 11
// baseline (197.861 us; speedup 1.0000x reference)
//
#include <hip/hip_runtime.h>

// Problem constants
#define D_MODEL 1024
#define NHEADS  16
#define HDIM    64
#define BATCH   2
#define SEQ     2048
#define M_TOK   (BATCH * SEQ)   // 4096

typedef unsigned short u16;
typedef unsigned int   u32;
typedef __attribute__((ext_vector_type(8))) short  short8;
typedef __attribute__((ext_vector_type(4))) float  floatx4;
typedef __attribute__((ext_vector_type(2))) u32    u32x2;

#define GLOBAL_AS __attribute__((address_space(1)))
#define LDS_AS    __attribute__((address_space(3)))

// async global->LDS, 16B per lane; LDS dst = wave-uniform base + lane*16 (m97 pattern)
static __device__ __forceinline__ void gload_lds16(const u16* g, u16* l) {
    __builtin_amdgcn_global_load_lds((const GLOBAL_AS u32*)g, (LDS_AS u32*)l, 16, 0, 0);
}

static __device__ __forceinline__ u16 f2bf(float f) {
    union { float f; u32 i; } v; v.f = f;
    u32 x = v.i;
    return (u16)((x + 0x7fffu + ((x >> 16) & 1u)) >> 16);
}

// pack 2 f32 -> 2 bf16 in one u32 (lo=a, hi=b), single VALU op
static __device__ __forceinline__ u32 cvtpk(float a, float b) {
    u32 r;
    asm("v_cvt_pk_bf16_f32 %0, %1, %2" : "=v"(r) : "v"(a), "v"(b));
    return r;
}

// load 8 fp32, RNE to bf16, pack as short8
static __device__ __forceinline__ short8 ld8_cvt(const float* __restrict__ p) {
    float4 f0 = *(const float4*)(p);
    float4 f1 = *(const float4*)(p + 4);
    short8 r;
    r[0] = (short)f2bf(f0.x); r[1] = (short)f2bf(f0.y);
    r[2] = (short)f2bf(f0.z); r[3] = (short)f2bf(f0.w);
    r[4] = (short)f2bf(f1.x); r[5] = (short)f2bf(f1.y);
    r[6] = (short)f2bf(f1.z); r[7] = (short)f2bf(f1.w);
    return r;
}

// ---------------------------------------------------------------------------
__global__ __launch_bounds__(256) void zerofill_k(float* __restrict__ out, int n) {
    int i = blockIdx.x * 256 + threadIdx.x;
    if (i < n) out[i] = 0.f;
}

// Fused prep, VECTORIZED. grid (32, 32, 5), block 256.
// z<4: 32x32 weight tile transpose: float4 loads -> LDS u16 [32][34] -> short8
//      stores. z==4: 16 floats/thread, 2x short8 stores.
__global__ __launch_bounds__(256) void prep_k(const float* __restrict__ x,
                                              const float* __restrict__ W0,
                                              const float* __restrict__ W1,
                                              const float* __restrict__ W2,
                                              const float* __restrict__ W3,
                                              u16* __restrict__ WtBase,
                                              u16* __restrict__ Xb) {
    int z = blockIdx.z;
    int t = threadIdx.x;
    if (z == 4) {
        int blk = blockIdx.y * 32 + blockIdx.x;          // 0..1023
        size_t i0 = ((size_t)blk * 256 + t) * 16;        // 16 floats/thread
        short8 v0 = ld8_cvt(x + i0);
        short8 v1 = ld8_cvt(x + i0 + 8);
        *(short8*)(Xb + i0)     = v0;
        *(short8*)(Xb + i0 + 8) = v1;
        return;
    }
    const float* W = (z == 0) ? W0 : (z == 1) ? W1 : (z == 2) ? W2 : W3;
    u16* Wt = WtBase + (size_t)z * 1024 * 1024;
    __shared__ u16 T[32][34];
    int bx = blockIdx.x * 32, by = blockIdx.y * 32;
    {
        int r = t >> 3, c4 = t & 7;                      // 32 rows x 8 float4
        float4 f = *(const float4*)(W + (size_t)(by + r) * 1024 + bx + c4 * 4);
        u32 lo = (u32)f2bf(f.x) | ((u32)f2bf(f.y) << 16);
        u32 hi = (u32)f2bf(f.z) | ((u32)f2bf(f.w) << 16);
        *(u32*)(&T[r][c4 * 4])     = lo;
        *(u32*)(&T[r][c4 * 4 + 2]) = hi;
    }
    __syncthreads();
    if (t < 128) {
        int n = t >> 2, seg = t & 3;                     // out row n, 8-k segment
        short8 v;
#pragma unroll
        for (int i = 0; i < 8; ++i) v[i] = (short)T[seg * 8 + i][n];
        *(short8*)(Wt + (size_t)(bx + n) * 1024 + by + seg * 8) = v;
    }
}

// ---------------------------------------------------------------------------
// GEMM core v3 (R8/R10 config — best measured): attn-style double-buffered
// single-barrier loop. prologue stages tile 0; per iter: __syncthreads()
// (drains DMA issued one iter ago), issue DMA(k+1), compute tile k.
// qkv BK=32 (dbuf 32KB, linear staging); out BK=64 (dbuf 48KB, both-sides
// XOR swizzle since 128B rows are bank-degenerate).
// MODE 0: C[row*1024+col] fp32(OUTF32) or bf16
// MODE 1: head-split [B,H,S,64] bf16
// MODE 2: head-split TRANSPOSED [B,H,64,S] bf16 (MI must be 4)
// ---------------------------------------------------------------------------
template <int MODE, int OUTF32, int MI, int BK>
static __device__ __forceinline__ void gemm_core(u16* __restrict__ smem,
                                                 const u16* __restrict__ A,
                                                 const u16* __restrict__ Bt,
                                                 const float* __restrict__ bias,
                                                 float scale,
                                                 void* __restrict__ C,
                                                 int m0, int n0) {
    constexpr int RG   = BK / 8;                 // granules per row
    constexpr int BUFG = (MI * 32 + 128) * RG;   // granules per buffer
    int tid  = threadIdx.x;
    int wave = tid >> 6, lane = tid & 63;
    int quad = lane >> 4, l15 = lane & 15;
    int wm = (wave & 1) * (MI * 16);
    int wn = (wave >> 1) * 64;

    // stage tile (k0) into buffer buf: A then B, linear LDS granules
    auto stage = [&](int buf, int k0) {
        u16* Asb = smem + (size_t)buf * BUFG * 8;
        u16* Bsb = Asb + MI * 32 * RG * 8;
#pragma unroll
        for (int t = 0; t < MI * 32 * RG / 256; ++t) {
            int a = t * 256 + tid;
            int row = a / RG, c = a & (RG - 1);
            int cs = (BK == 64) ? (c ^ (row & 7)) : c;
            gload_lds16(A + (size_t)(m0 + row) * 1024 + k0 + cs * 8,
                        Asb + (size_t)a * 8);
        }
#pragma unroll
        for (int t = 0; t < 128 * RG / 256; ++t) {
            int a = t * 256 + tid;
            int row = a / RG, c = a & (RG - 1);
            int cs = (BK == 64) ? (c ^ (row & 7)) : c;
            gload_lds16(Bt + (size_t)(n0 + row) * 1024 + k0 + cs * 8,
                        Bsb + (size_t)a * 8);
        }
    };

    floatx4 acc[MI][4] = {};
    stage(0, 0);

    for (int k0 = 0; k0 < 1024; k0 += BK) {
        int cur = (k0 / BK) & 1;
        __syncthreads();                 // DMA(cur) issued one iter ago: landed
        if (k0 + BK < 1024) stage(cur ^ 1, k0 + BK);

        u16* Asb = smem + (size_t)cur * BUFG * 8;
        u16* Bsb = Asb + MI * 32 * RG * 8;
#pragma unroll
        for (int h = 0; h < BK / 32; ++h) {
            short8 af[MI], bfr[4];
#pragma unroll
            for (int i = 0; i < MI; ++i) {
                int row = wm + i * 16 + l15;
                int g = (BK == 64) ? ((h * 4 + quad) ^ (l15 & 7)) : quad;
                af[i] = *(const short8*)(Asb + (size_t)row * BK + g * 8);
            }
#pragma unroll
            for (int j = 0; j < 4; ++j) {
                int row = wn + j * 16 + l15;
                int g = (BK == 64) ? ((h * 4 + quad) ^ (l15 & 7)) : quad;
                bfr[j] = *(const short8*)(Bsb + (size_t)row * BK + g * 8);
            }
#pragma unroll
            for (int i = 0; i < MI; ++i)
#pragma unroll
                for (int j = 0; j < 4; ++j)
                    acc[i][j] = __builtin_amdgcn_mfma_f32_16x16x32_bf16(af[i], bfr[j], acc[i][j], 0, 0, 0);
        }
    }

    if constexpr (MODE == 2) {
        // Transposed epilogue: two 64-col passes through LDS T[64][136], then
        // coalesced 256B row-bursts to V^T [B,H,64,S]. T aliases the buffers,
        // so sync before overwriting (loop no longer ends with one).
        __syncthreads();
        u16* T = smem;   // 64*136 u16
        int bb = m0 >> 11;
#pragma unroll
        for (int p = 0; p < 2; ++p) {
            if (p) __syncthreads();          // prior copy reads complete
            if ((wave >> 1) == p) {
#pragma unroll
                for (int j = 0; j < 4; ++j) {
                    int dcol = j * 16 + l15;                 // 0..63 within pass
                    float bv = bias[n0 + p * 64 + dcol];
#pragma unroll
                    for (int i = 0; i < MI; ++i) {
#pragma unroll
                        for (int rr = 0; rr < 2; ++rr) {
                            int srow = wm + i * 16 + quad * 4 + rr * 2;
                            u16 lo = f2bf((acc[i][j][rr * 2]     + bv) * scale);
                            u16 hi = f2bf((acc[i][j][rr * 2 + 1] + bv) * scale);
                            *(u32*)(T + dcol * 136 + srow) = (u32)lo | ((u32)hi << 16);
                        }
                    }
                }
            }
            __syncthreads();                 // T visible to all
            int d  = tid >> 2;               // 0..63
            int sc = (tid & 3) * 32;
            int col = n0 + p * 64 + d;
            int h = col >> 6, dd = col & 63;
            int s0 = (m0 & 2047) + sc;
            size_t gbase = (((size_t)bb * NHEADS + h) * HDIM + dd) * SEQ + s0;
#pragma unroll
            for (int c = 0; c < 4; ++c)
                *(short8*)((u16*)C + gbase + c * 8) = *(const short8*)(T + d * 136 + sc + c * 8);
        }
        return;
    }

    // epilogue (MODE 0/1): C/D layout col=lane&15, row=quad*4+reg
#pragma unroll
    for (int j = 0; j < 4; ++j) {
        int col = n0 + wn + j * 16 + l15;
        float bv = bias[col];
#pragma unroll
        for (int i = 0; i < MI; ++i) {
#pragma unroll
            for (int r = 0; r < 4; ++r) {
                int row = m0 + wm + i * 16 + quad * 4 + r;
                float v = (acc[i][j][r] + bv) * scale;
                size_t idx;
                if (MODE == 0) {
                    idx = (size_t)row * 1024 + col;
                } else {  // MODE 1: [B,H,S,64]
                    int b = row >> 11, s = row & 2047;
                    int h = col >> 6,  d = col & 63;
                    idx = (((size_t)b * NHEADS + h) * SEQ + s) * HDIM + d;
                }
                if constexpr (OUTF32) ((float*)C)[idx] = v;
                else                  ((u16*)C)[idx] = f2bf(v);
            }
        }
    }
}

// QKV fused: grid (8, 32, 3) = 768 blocks (3/CU), BK=32 dbuf (32KB x 3/CU).
// __launch_bounds__(256,3) pins VGPR<=170 (R5: -17us vs unpinned).
// R10 XCD swizzle: XCD x owns m-panels {4x..4x+3}; within XCD, n fastest,
// then z, then m -> A-panel fetched into one XCD L2, reused by 23 blocks.
__global__ __launch_bounds__(256, 3) void gemm_qkv(const u16* __restrict__ X,
                                                   const u16* __restrict__ WtBase,
                                                   const float* __restrict__ bq,
                                                   const float* __restrict__ bk,
                                                   const float* __restrict__ bv,
                                                   u16* __restrict__ OutBase) {
    __shared__ __align__(16) u16 smem[16384];   // 2 x (As 128x32 + Bs 128x32); T=8704 aliases
    int hw  = blockIdx.z * 256 + blockIdx.y * 8 + blockIdx.x;
    int x   = hw & 7;                // XCD (round-robin)
    int i   = hw >> 3;               // 0..95 within XCD
    int ml  = i / 24;                // 0..3
    int rem = i - ml * 24;
    int z   = rem >> 3;              // 0..2
    int n0  = (rem & 7) * 128;
    int m0  = (x * 4 + ml) * 128;
    const u16* Bt     = WtBase + (size_t)z * 1024 * 1024;
    const float* bias = (z == 0) ? bq : (z == 1) ? bk : bv;
    u16* C            = OutBase + (size_t)z * (size_t)M_TOK * 1024;
    if (z == 2)
        gemm_core<2, 0, 4, 32>(smem, X, Bt, bias, 1.0f, C, m0, n0);
    else if (z == 0)
        gemm_core<1, 0, 4, 32>(smem, X, Bt, bias, 0.18033688011112042f /* log2(e)/8 */, C, m0, n0);
    else
        gemm_core<1, 0, 4, 32>(smem, X, Bt, bias, 1.0f, C, m0, n0);
}

// Output projection: grid (8, 64) = 512 blocks (2/CU), BK=64 dbuf (48KB x 2).
// m-grouped XCD swizzle: XCD x owns m-tiles {8x..8x+7}; per-XCD working set
// A 1MB + B 2MB < 4MB L2. fp32 out.
__global__ __launch_bounds__(256, 2) void gemm_out(const u16* __restrict__ A,
                                                   const u16* __restrict__ Bt,
                                                   const float* __restrict__ bias,
                                                   float* __restrict__ C) {
    __shared__ __align__(16) u16 smem[24576];   // 2 x (As 64x64 + Bs 128x64)
    int hw = blockIdx.y * 8 + blockIdx.x;
    int x  = hw & 7;
    int i  = hw >> 3;                // 0..63
    int m0 = (x * 8 + (i >> 3)) * 64;
    int n0 = (i & 7) * 128;
    gemm_core<0, 1, 2, 64>(smem, A, Bt, bias, 1.0f, C, m0, n0);
}

// ---------------------------------------------------------------------------
// Flash attention v12: 32 q-rows per wave. grid (SEQ/128, BATCH*NHEADS) = 512
// blocks (UNCHANGED), but 256 threads / 4 waves per block, each wave owning
// 32 q-rows (two 16-row halves qh=0/1).
// R10 pipe-budget post-mortem: v10's LDS pipe ran ~64% of the wall (32
// ds_read_b128 K/V frags per wave per iter, same 16KB K re-read by all 8
// waves); trans 41%, MFMA 29%. v12 doubles q-rows/wave so each K/V b128 read
// feeds TWO MFMAs -> per-CU LDS traffic drops ~45%, pipes balanced.
// Waves/CU halves to 8 (2/SIMD) — intentional: ILP over TLP.
// VGPR ~165 (s[8][2], o[4][2]) at (256,2) cap 256, no spill.
// All frag/swizzle math identical per q-half. LDS 75776 B -> 2 blocks/CU.
// ---------------------------------------------------------------------------
#define PST2 40
__global__ __launch_bounds__(256, 2) void attn_k(const u16* __restrict__ Q,
                                                 const u16* __restrict__ K,
                                                 const u16* __restrict__ Vt_g,
                                                 u16* __restrict__ O) {
    __shared__ __align__(16) u16 Vt[2][64 * 128];     // V^T tile, swizzled, 2x16KB
    __shared__ __align__(16) u16 Kt[2][128 * 64];     // K tile, swizzled, 2x16KB
    __shared__ __align__(16) u16 Pl[4][2 * 16 * PST2];// per-wave P chunk x2 qh, 10240 B

    int tid  = threadIdx.x;
    int wave = tid >> 6, lane = tid & 63;
    int quad = lane >> 4, l15 = lane & 15;
    int bh = blockIdx.y;
    int b = bh >> 4, h = bh & 15;
    const u16* Qb = Q    + (size_t)bh * SEQ * HDIM;
    const u16* Kb = K    + (size_t)bh * SEQ * HDIM;
    const u16* Vb = Vt_g + (size_t)bh * HDIM * SEQ;   // [d][s]
    int q0 = blockIdx.x * 128 + wave * 32;

    // Q A/B-frags (pre-scaled), per q-half: [m=l15][k=quad*8+j]
    short8 qf0[2], qf1[2];
#pragma unroll
    for (int qh = 0; qh < 2; ++qh) {
        const u16* qp = Qb + (size_t)(q0 + qh * 16 + l15) * 64;
        qf0[qh] = *(const short8*)(qp + quad * 8);
        qf1[qh] = *(const short8*)(qp + 32 + quad * 8);
    }

    // constant ones B-frag (bf16 1.0 = 0x3F80) for MFMA row-sums
    short8 onesf;
#pragma unroll
    for (int i = 0; i < 8; ++i) onesf[i] = (short)0x3F80;

    floatx4 o[4][2] = {};
    floatx4 o_sum[2] = {};

    // DMA K+V tile 0 into buffer 0 (1024 granules each / 256 threads = 4 rounds)
    {
#pragma unroll
        for (int rnd = 0; rnd < 4; ++rnd) {
            int g = rnd * 256 + tid;
            int vrow = g >> 4, vc = g & 15;
            gload_lds16(Vb + (size_t)vrow * SEQ + (vc ^ (vrow & 15)) * 8,
                        Vt[0] + (size_t)g * 8);
            int krow = g >> 3, kc = g & 7;
            gload_lds16(Kb + (size_t)krow * 64 + (kc ^ (krow & 7)) * 8,
                        Kt[0] + (size_t)g * 8);
        }
    }

    for (int it = 0; it < SEQ / 128; ++it) {
        int kv0 = it * 128;
        __syncthreads();   // drains DMA(it) [issued one iter ago]

        // --- issue K+V DMA(it+1) into the other buffer ---
        if (it + 1 < SEQ / 128) {
            u16* vdst = Vt[(it + 1) & 1];
            u16* kdst = Kt[(it + 1) & 1];
#pragma unroll
            for (int rnd = 0; rnd < 4; ++rnd) {
                int g = rnd * 256 + tid;
                int vrow = g >> 4, vc = g & 15;
                gload_lds16(Vb + (size_t)vrow * SEQ + kv0 + 128 + (vc ^ (vrow & 15)) * 8,
                            vdst + (size_t)g * 8);
                int krow = g >> 3, kc = g & 7;
                gload_lds16(Kb + (size_t)(kv0 + 128 + krow) * 64 + (kc ^ (krow & 7)) * 8,
                            kdst + (size_t)g * 8);
            }
        }

        // --- S^T = K @ Q^T, K frags from LDS read ONCE, used for BOTH q-halves
        // s[j][qh] layout: col=l15 = q (within half), row=quad*4+r = kv
        const u16* kb = Kt[it & 1];
        floatx4 s[8][2];
        __builtin_amdgcn_s_setprio(1);
#pragma unroll
        for (int j = 0; j < 8; ++j) {
            int row = j * 16 + l15;                    // row&7 == l15&7
            const u16* kr = kb + (size_t)row * 64;
            short8 k0 = *(const short8*)(kr + ((quad ^ (l15 & 7)) * 8));
            short8 k1 = *(const short8*)(kr + (((quad + 4) ^ (l15 & 7)) * 8));
#pragma unroll
            for (int qh = 0; qh < 2; ++qh) {
                floatx4 a = {};
                a = __builtin_amdgcn_mfma_f32_16x16x32_bf16(k0, qf0[qh], a, 0, 0, 0);
                a = __builtin_amdgcn_mfma_f32_16x16x32_bf16(k1, qf1[qh], a, 0, 0, 0);
                s[j][qh] = a;
            }
        }
        __builtin_amdgcn_s_setprio(0);

        // --- per-32-kv chunk: p = exp2(s), pack+store P (both halves), then
        //     PV with V frags read ONCE per dj, used for both q-halves ---
        const u16* vb = Vt[it & 1];
#pragma unroll
        for (int kh = 0; kh < 4; ++kh) {
#pragma unroll
            for (int qh = 0; qh < 2; ++qh) {
#pragma unroll
                for (int t = 0; t < 2; ++t) {
                    int j = kh * 2 + t;
                    float p0 = exp2f(s[j][qh][0]), p1 = exp2f(s[j][qh][1]);
                    float p2 = exp2f(s[j][qh][2]), p3 = exp2f(s[j][qh][3]);
                    u32 w0 = cvtpk(p0, p1), w1 = cvtpk(p2, p3);
                    // kv' = t*16 + quad*4 + r  (4 contiguous bf16 -> one b64)
                    *(u32x2*)(&Pl[wave][qh * 16 * PST2 + l15 * PST2 + t * 16 + quad * 4]) =
                        (u32x2){w0, w1};
                }
            }
            // consume: A-frag P[m=l15=q][k=quad*8+i], one per q-half
            short8 pf[2];
#pragma unroll
            for (int qh = 0; qh < 2; ++qh)
                pf[qh] = *(const short8*)(&Pl[wave][qh * 16 * PST2 + l15 * PST2 + quad * 8]);
            __builtin_amdgcn_s_setprio(1);
#pragma unroll
            for (int dj = 0; dj < 4; ++dj) {
                int row = dj * 16 + l15;
                int cg  = kh * 4 + quad;
                short8 vf = *(const short8*)(&vb[(row * 16 + (cg ^ l15)) * 8]);
#pragma unroll
                for (int qh = 0; qh < 2; ++qh)
                    o[dj][qh] = __builtin_amdgcn_mfma_f32_16x16x32_bf16(pf[qh], vf, o[dj][qh], 0, 0, 0);
            }
#pragma unroll
            for (int qh = 0; qh < 2; ++qh)
                o_sum[qh] = __builtin_amdgcn_mfma_f32_16x16x32_bf16(pf[qh], onesf, o_sum[qh], 0, 0, 0);
            __builtin_amdgcn_s_setprio(0);
        }
    }

    // --- epilogue: o_sum[qh][r] = full row sum for q=q0+qh*16+quad*4+r ---
#pragma unroll
    for (int qh = 0; qh < 2; ++qh) {
#pragma unroll
        for (int r = 0; r < 4; ++r) {
            float invq = 1.f / o_sum[qh][r];
            int srow = q0 + qh * 16 + quad * 4 + r;
            size_t base = ((size_t)b * SEQ + srow) * D_MODEL + h * HDIM;
#pragma unroll
            for (int dj = 0; dj < 4; ++dj)
                O[base + dj * 16 + l15] = f2bf(o[dj][qh][r] * invq);
        }
    }
}

// ---------------------------------------------------------------------------
extern "C" void kernel_launch(void* const* d_in, const int* in_sizes, int n_in,
                              void* d_out, int out_size, void* d_ws, size_t ws_size,
                              hipStream_t stream) {
    const float* x  = (const float*)d_in[0];
    const float* Wq = (const float*)d_in[1];
    const float* bq = (const float*)d_in[2];
    const float* Wk = (const float*)d_in[3];
    const float* bk = (const float*)d_in[4];
    const float* Wv = (const float*)d_in[5];
    const float* bv = (const float*)d_in[6];
    const float* Wo = (const float*)d_in[7];
    const float* bo = (const float*)d_in[8];
    float* out = (float*)d_out;

    char* ws = (char*)d_ws;
    const size_t WSZ = (size_t)1024 * 1024 * sizeof(u16);   // 2MB per bf16 weight
    const size_t QSZ = (size_t)M_TOK * 1024 * sizeof(u16);  // 8MB per bf16 activation
    const size_t NEED = 4 * WSZ + 4 * QSZ;                  // 40MB

    if (ws_size < NEED) {
        zerofill_k<<<dim3((out_size + 255) / 256), 256, 0, stream>>>(out, out_size);
        return;
    }

    u16* wtq = (u16*)(ws);                       // wt q,k,v,o contiguous
    u16* wto = (u16*)(ws + 3 * WSZ);
    u16* Qw  = (u16*)(ws + 4 * WSZ);             // Q,K [B,H,S,64]; V^T [B,H,64,S]
    u16* Kw  = (u16*)(ws + 4 * WSZ + QSZ);
    u16* Vw  = (u16*)(ws + 4 * WSZ + 2 * QSZ);
    u16* Xb  = (u16*)(ws + 4 * WSZ + 3 * QSZ);   // x bf16; dead after gemm_qkv
    u16* Aw  = Xb;                               // attention output reuses Xb

    prep_k<<<dim3(32, 32, 5), 256, 0, stream>>>(x, Wq, Wk, Wv, Wo, wtq, Xb);

    gemm_qkv<<<dim3(8, 32, 3), 256, 0, stream>>>(Xb, wtq, bq, bk, bv, Qw);
    attn_k<<<dim3(SEQ / 128, BATCH * NHEADS), 256, 0, stream>>>(Qw, Kw, Vw, Aw);
    gemm_out<<<dim3(8, 64), 256, 0, stream>>>(Aw, wto, bo, out);
}

// Round 12
// 193.308 us; speedup vs baseline: 1.0236x; 1.0236x over previous
//
#include <hip/hip_runtime.h>

// Problem constants
#define D_MODEL 1024
#define NHEADS  16
#define HDIM    64
#define BATCH   2
#define SEQ     2048
#define M_TOK   (BATCH * SEQ)   // 4096

typedef unsigned short u16;
typedef unsigned int   u32;
typedef __attribute__((ext_vector_type(8))) short  short8;
typedef __attribute__((ext_vector_type(4))) float  floatx4;
typedef __attribute__((ext_vector_type(2))) u32    u32x2;

#define GLOBAL_AS __attribute__((address_space(1)))
#define LDS_AS    __attribute__((address_space(3)))

// async global->LDS, 16B per lane; LDS dst = wave-uniform base + lane*16 (m97 pattern)
static __device__ __forceinline__ void gload_lds16(const u16* g, u16* l) {
    __builtin_amdgcn_global_load_lds((const GLOBAL_AS u32*)g, (LDS_AS u32*)l, 16, 0, 0);
}

static __device__ __forceinline__ u16 f2bf(float f) {
    union { float f; u32 i; } v; v.f = f;
    u32 x = v.i;
    return (u16)((x + 0x7fffu + ((x >> 16) & 1u)) >> 16);
}

// pack 2 f32 -> 2 bf16 in one u32 (lo=a, hi=b), single VALU op
static __device__ __forceinline__ u32 cvtpk(float a, float b) {
    u32 r;
    asm("v_cvt_pk_bf16_f32 %0, %1, %2" : "=v"(r) : "v"(a), "v"(b));
    return r;
}

// load 8 fp32, RNE to bf16, pack as short8
static __device__ __forceinline__ short8 ld8_cvt(const float* __restrict__ p) {
    float4 f0 = *(const float4*)(p);
    float4 f1 = *(const float4*)(p + 4);
    short8 r;
    r[0] = (short)f2bf(f0.x); r[1] = (short)f2bf(f0.y);
    r[2] = (short)f2bf(f0.z); r[3] = (short)f2bf(f0.w);
    r[4] = (short)f2bf(f1.x); r[5] = (short)f2bf(f1.y);
    r[6] = (short)f2bf(f1.z); r[7] = (short)f2bf(f1.w);
    return r;
}

// ---------------------------------------------------------------------------
__global__ __launch_bounds__(256) void zerofill_k(float* __restrict__ out, int n) {
    int i = blockIdx.x * 256 + threadIdx.x;
    if (i < n) out[i] = 0.f;
}

// Fused prep, VECTORIZED. grid (32, 32, 5), block 256.
// z<4: 32x32 weight tile transpose: float4 loads -> LDS u16 [32][34] -> short8
//      stores. z==4: 16 floats/thread, 2x short8 stores.
__global__ __launch_bounds__(256) void prep_k(const float* __restrict__ x,
                                              const float* __restrict__ W0,
                                              const float* __restrict__ W1,
                                              const float* __restrict__ W2,
                                              const float* __restrict__ W3,
                                              u16* __restrict__ WtBase,
                                              u16* __restrict__ Xb) {
    int z = blockIdx.z;
    int t = threadIdx.x;
    if (z == 4) {
        int blk = blockIdx.y * 32 + blockIdx.x;          // 0..1023
        size_t i0 = ((size_t)blk * 256 + t) * 16;        // 16 floats/thread
        short8 v0 = ld8_cvt(x + i0);
        short8 v1 = ld8_cvt(x + i0 + 8);
        *(short8*)(Xb + i0)     = v0;
        *(short8*)(Xb + i0 + 8) = v1;
        return;
    }
    const float* W = (z == 0) ? W0 : (z == 1) ? W1 : (z == 2) ? W2 : W3;
    u16* Wt = WtBase + (size_t)z * 1024 * 1024;
    __shared__ u16 T[32][34];
    int bx = blockIdx.x * 32, by = blockIdx.y * 32;
    {
        int r = t >> 3, c4 = t & 7;                      // 32 rows x 8 float4
        float4 f = *(const float4*)(W + (size_t)(by + r) * 1024 + bx + c4 * 4);
        u32 lo = (u32)f2bf(f.x) | ((u32)f2bf(f.y) << 16);
        u32 hi = (u32)f2bf(f.z) | ((u32)f2bf(f.w) << 16);
        *(u32*)(&T[r][c4 * 4])     = lo;
        *(u32*)(&T[r][c4 * 4 + 2]) = hi;
    }
    __syncthreads();
    if (t < 128) {
        int n = t >> 2, seg = t & 3;                     // out row n, 8-k segment
        short8 v;
#pragma unroll
        for (int i = 0; i < 8; ++i) v[i] = (short)T[seg * 8 + i][n];
        *(short8*)(Wt + (size_t)(bx + n) * 1024 + by + seg * 8) = v;
    }
}

// ---------------------------------------------------------------------------
// GEMM core v3 (R8/R10 config — best measured): attn-style double-buffered
// single-barrier loop. prologue stages tile 0; per iter: __syncthreads()
// (drains DMA issued one iter ago), issue DMA(k+1), compute tile k.
// qkv BK=32 (dbuf 32KB, linear staging); out BK=64 (dbuf 48KB, both-sides
// XOR swizzle since 128B rows are bank-degenerate).
// MODE 0: C[row*1024+col] fp32(OUTF32) or bf16
// MODE 1: head-split [B,H,S,64] bf16
// MODE 2: head-split TRANSPOSED [B,H,64,S] bf16 (MI must be 4)
// ---------------------------------------------------------------------------
template <int MODE, int OUTF32, int MI, int BK>
static __device__ __forceinline__ void gemm_core(u16* __restrict__ smem,
                                                 const u16* __restrict__ A,
                                                 const u16* __restrict__ Bt,
                                                 const float* __restrict__ bias,
                                                 float scale,
                                                 void* __restrict__ C,
                                                 int m0, int n0) {
    constexpr int RG   = BK / 8;                 // granules per row
    constexpr int BUFG = (MI * 32 + 128) * RG;   // granules per buffer
    int tid  = threadIdx.x;
    int wave = tid >> 6, lane = tid & 63;
    int quad = lane >> 4, l15 = lane & 15;
    int wm = (wave & 1) * (MI * 16);
    int wn = (wave >> 1) * 64;

    // stage tile (k0) into buffer buf: A then B, linear LDS granules
    auto stage = [&](int buf, int k0) {
        u16* Asb = smem + (size_t)buf * BUFG * 8;
        u16* Bsb = Asb + MI * 32 * RG * 8;
#pragma unroll
        for (int t = 0; t < MI * 32 * RG / 256; ++t) {
            int a = t * 256 + tid;
            int row = a / RG, c = a & (RG - 1);
            int cs = (BK == 64) ? (c ^ (row & 7)) : c;
            gload_lds16(A + (size_t)(m0 + row) * 1024 + k0 + cs * 8,
                        Asb + (size_t)a * 8);
        }
#pragma unroll
        for (int t = 0; t < 128 * RG / 256; ++t) {
            int a = t * 256 + tid;
            int row = a / RG, c = a & (RG - 1);
            int cs = (BK == 64) ? (c ^ (row & 7)) : c;
            gload_lds16(Bt + (size_t)(n0 + row) * 1024 + k0 + cs * 8,
                        Bsb + (size_t)a * 8);
        }
    };

    floatx4 acc[MI][4] = {};
    stage(0, 0);

    for (int k0 = 0; k0 < 1024; k0 += BK) {
        int cur = (k0 / BK) & 1;
        __syncthreads();                 // DMA(cur) issued one iter ago: landed
        if (k0 + BK < 1024) stage(cur ^ 1, k0 + BK);

        u16* Asb = smem + (size_t)cur * BUFG * 8;
        u16* Bsb = Asb + MI * 32 * RG * 8;
#pragma unroll
        for (int h = 0; h < BK / 32; ++h) {
            short8 af[MI], bfr[4];
#pragma unroll
            for (int i = 0; i < MI; ++i) {
                int row = wm + i * 16 + l15;
                int g = (BK == 64) ? ((h * 4 + quad) ^ (l15 & 7)) : quad;
                af[i] = *(const short8*)(Asb + (size_t)row * BK + g * 8);
            }
#pragma unroll
            for (int j = 0; j < 4; ++j) {
                int row = wn + j * 16 + l15;
                int g = (BK == 64) ? ((h * 4 + quad) ^ (l15 & 7)) : quad;
                bfr[j] = *(const short8*)(Bsb + (size_t)row * BK + g * 8);
            }
#pragma unroll
            for (int i = 0; i < MI; ++i)
#pragma unroll
                for (int j = 0; j < 4; ++j)
                    acc[i][j] = __builtin_amdgcn_mfma_f32_16x16x32_bf16(af[i], bfr[j], acc[i][j], 0, 0, 0);
        }
    }

    if constexpr (MODE == 2) {
        // Transposed epilogue: two 64-col passes through LDS T[64][136], then
        // coalesced 256B row-bursts to V^T [B,H,64,S]. T aliases the buffers,
        // so sync before overwriting (loop no longer ends with one).
        __syncthreads();
        u16* T = smem;   // 64*136 u16
        int bb = m0 >> 11;
#pragma unroll
        for (int p = 0; p < 2; ++p) {
            if (p) __syncthreads();          // prior copy reads complete
            if ((wave >> 1) == p) {
#pragma unroll
                for (int j = 0; j < 4; ++j) {
                    int dcol = j * 16 + l15;                 // 0..63 within pass
                    float bv = bias[n0 + p * 64 + dcol];
#pragma unroll
                    for (int i = 0; i < MI; ++i) {
#pragma unroll
                        for (int rr = 0; rr < 2; ++rr) {
                            int srow = wm + i * 16 + quad * 4 + rr * 2;
                            u16 lo = f2bf((acc[i][j][rr * 2]     + bv) * scale);
                            u16 hi = f2bf((acc[i][j][rr * 2 + 1] + bv) * scale);
                            *(u32*)(T + dcol * 136 + srow) = (u32)lo | ((u32)hi << 16);
                        }
                    }
                }
            }
            __syncthreads();                 // T visible to all
            int d  = tid >> 2;               // 0..63
            int sc = (tid & 3) * 32;
            int col = n0 + p * 64 + d;
            int h = col >> 6, dd = col & 63;
            int s0 = (m0 & 2047) + sc;
            size_t gbase = (((size_t)bb * NHEADS + h) * HDIM + dd) * SEQ + s0;
#pragma unroll
            for (int c = 0; c < 4; ++c)
                *(short8*)((u16*)C + gbase + c * 8) = *(const short8*)(T + d * 136 + sc + c * 8);
        }
        return;
    }

    // epilogue (MODE 0/1): C/D layout col=lane&15, row=quad*4+reg
#pragma unroll
    for (int j = 0; j < 4; ++j) {
        int col = n0 + wn + j * 16 + l15;
        float bv = bias[col];
#pragma unroll
        for (int i = 0; i < MI; ++i) {
#pragma unroll
            for (int r = 0; r < 4; ++r) {
                int row = m0 + wm + i * 16 + quad * 4 + r;
                float v = (acc[i][j][r] + bv) * scale;
                size_t idx;
                if (MODE == 0) {
                    idx = (size_t)row * 1024 + col;
                } else {  // MODE 1: [B,H,S,64]
                    int b = row >> 11, s = row & 2047;
                    int h = col >> 6,  d = col & 63;
                    idx = (((size_t)b * NHEADS + h) * SEQ + s) * HDIM + d;
                }
                if constexpr (OUTF32) ((float*)C)[idx] = v;
                else                  ((u16*)C)[idx] = f2bf(v);
            }
        }
    }
}

// QKV fused: grid (8, 32, 3) = 768 blocks (3/CU), BK=32 dbuf (32KB x 3/CU).
// __launch_bounds__(256,3) pins VGPR<=170 (R5: -17us vs unpinned).
// R10 XCD swizzle: XCD x owns m-panels {4x..4x+3}; within XCD, n fastest,
// then z, then m -> A-panel fetched into one XCD L2, reused by 23 blocks.
__global__ __launch_bounds__(256, 3) void gemm_qkv(const u16* __restrict__ X,
                                                   const u16* __restrict__ WtBase,
                                                   const float* __restrict__ bq,
                                                   const float* __restrict__ bk,
                                                   const float* __restrict__ bv,
                                                   u16* __restrict__ OutBase) {
    __shared__ __align__(16) u16 smem[16384];   // 2 x (As 128x32 + Bs 128x32); T=8704 aliases
    int hw  = blockIdx.z * 256 + blockIdx.y * 8 + blockIdx.x;
    int x   = hw & 7;                // XCD (round-robin)
    int i   = hw >> 3;               // 0..95 within XCD
    int ml  = i / 24;                // 0..3
    int rem = i - ml * 24;
    int z   = rem >> 3;              // 0..2
    int n0  = (rem & 7) * 128;
    int m0  = (x * 4 + ml) * 128;
    const u16* Bt     = WtBase + (size_t)z * 1024 * 1024;
    const float* bias = (z == 0) ? bq : (z == 1) ? bk : bv;
    u16* C            = OutBase + (size_t)z * (size_t)M_TOK * 1024;
    if (z == 2)
        gemm_core<2, 0, 4, 32>(smem, X, Bt, bias, 1.0f, C, m0, n0);
    else if (z == 0)
        gemm_core<1, 0, 4, 32>(smem, X, Bt, bias, 0.18033688011112042f /* log2(e)/8 */, C, m0, n0);
    else
        gemm_core<1, 0, 4, 32>(smem, X, Bt, bias, 1.0f, C, m0, n0);
}

// Output projection: grid (8, 64) = 512 blocks (2/CU), BK=64 dbuf (48KB x 2).
// m-grouped XCD swizzle: XCD x owns m-tiles {8x..8x+7}; per-XCD working set
// A 1MB + B 2MB < 4MB L2. fp32 out.
__global__ __launch_bounds__(256, 2) void gemm_out(const u16* __restrict__ A,
                                                   const u16* __restrict__ Bt,
                                                   const float* __restrict__ bias,
                                                   float* __restrict__ C) {
    __shared__ __align__(16) u16 smem[24576];   // 2 x (As 64x64 + Bs 128x64)
    int hw = blockIdx.y * 8 + blockIdx.x;
    int x  = hw & 7;
    int i  = hw >> 3;                // 0..63
    int m0 = (x * 8 + (i >> 3)) * 64;
    int n0 = (i & 7) * 128;
    gemm_core<0, 1, 2, 64>(smem, A, Bt, bias, 1.0f, C, m0, n0);
}

// ---------------------------------------------------------------------------
// Flash attention v13 = v10 (proven 66.3us) + HEAD-GROUPED XCD SWIZZLE.
// R11 post-mortem: v12 (2x q-rows/wave, half LDS traffic) was NEUTRAL ->
// attn is not LDS-bound; all structural variants land at 66-67us with ~27%
// idle. Remaining untried axis: FETCH_SIZE 70MB vs ~25MB ideal — the 16
// q-blocks of each head are scattered round-robin over 8 XCDs, so each
// head's 512KB K/V set is re-fetched by multiple XCDs and DMAs miss L2
// (~900cy HBM latency). v13: XCD x owns heads {4x..4x+3} (all 16 q-blocks);
// per-XCD K/V set = 2MB < 4MB L2 -> K/V fetched from HBM once per XCD,
// DMA hits L2. Grid 512 = exactly 2/CU, bijective, zero-cost.
// grid (SEQ/128, BATCH*NHEADS), 512 threads (8 waves).
// ---------------------------------------------------------------------------
#define PST2 40
__global__ __launch_bounds__(512, 3) void attn_k(const u16* __restrict__ Q,
                                                 const u16* __restrict__ K,
                                                 const u16* __restrict__ Vt_g,
                                                 u16* __restrict__ O) {
    __shared__ __align__(16) u16 Vt[2][64 * 128];   // V^T tile, swizzled granules, 2x16KB
    __shared__ __align__(16) u16 Kt[2][128 * 64];   // K tile, swizzled granules, 2x16KB
    __shared__ __align__(16) u16 Pl[8][16 * PST2];  // per-wave P chunk, 10240 B

    int tid  = threadIdx.x;
    int wave = tid >> 6, lane = tid & 63;
    int quad = lane >> 4, l15 = lane & 15;

    // head-grouped XCD swizzle: hw = y*16 + x (x fastest, round-robin XCD)
    int hw  = blockIdx.y * 16 + blockIdx.x;
    int xcd = hw & 7, i = hw >> 3;       // i in 0..63
    int bh  = xcd * 4 + (i >> 4);        // 4 heads per XCD
    int qb  = i & 15;                    // q-block within head

    int b = bh >> 4, h = bh & 15;
    const u16* Qb = Q    + (size_t)bh * SEQ * HDIM;
    const u16* Kb = K    + (size_t)bh * SEQ * HDIM;
    const u16* Vb = Vt_g + (size_t)bh * HDIM * SEQ;   // [d][s]
    int q0 = qb * 128 + wave * 16;

    // Q A/B-frags (pre-scaled): [m=l15][k=quad*8+j]
    short8 qf0 = *(const short8*)(Qb + (size_t)(q0 + l15) * 64 + quad * 8);
    short8 qf1 = *(const short8*)(Qb + (size_t)(q0 + l15) * 64 + 32 + quad * 8);

    // constant ones B-frag (bf16 1.0 = 0x3F80) for MFMA row-sums
    short8 onesf;
#pragma unroll
    for (int ii = 0; ii < 8; ++ii) onesf[ii] = (short)0x3F80;

    floatx4 o[4] = {};
    floatx4 o_sum = {};   // row-sums of P, same D-layout as o (row=q, cols dup)

    // DMA K+V tile 0 into buffer 0 (each 1024 granules / 512 threads = 2 rounds)
    {
#pragma unroll
        for (int rnd = 0; rnd < 2; ++rnd) {
            int g = rnd * 512 + tid;
            int vrow = g >> 4, vc = g & 15;
            gload_lds16(Vb + (size_t)vrow * SEQ + (vc ^ (vrow & 15)) * 8,
                        Vt[0] + (size_t)g * 8);
            int krow = g >> 3, kc = g & 7;
            gload_lds16(Kb + (size_t)krow * 64 + (kc ^ (krow & 7)) * 8,
                        Kt[0] + (size_t)g * 8);
        }
    }

    for (int it = 0; it < SEQ / 128; ++it) {
        int kv0 = it * 128;
        __syncthreads();   // drains DMA(it) [issued one iter ago]

        // --- issue K+V DMA(it+1) into the other buffer ---
        if (it + 1 < SEQ / 128) {
            u16* vdst = Vt[(it + 1) & 1];
            u16* kdst = Kt[(it + 1) & 1];
#pragma unroll
            for (int rnd = 0; rnd < 2; ++rnd) {
                int g = rnd * 512 + tid;
                int vrow = g >> 4, vc = g & 15;
                gload_lds16(Vb + (size_t)vrow * SEQ + kv0 + 128 + (vc ^ (vrow & 15)) * 8,
                            vdst + (size_t)g * 8);
                int krow = g >> 3, kc = g & 7;
                gload_lds16(Kb + (size_t)(kv0 + 128 + krow) * 64 + (kc ^ (krow & 7)) * 8,
                            kdst + (size_t)g * 8);
            }
        }

        // --- S^T = K @ Q^T, K frags from LDS (swizzled read) ---
        // s[j] layout: col=l15 = q, row=quad*4+r = kv within j-block
        const u16* kb = Kt[it & 1];
        floatx4 s[8];
        __builtin_amdgcn_s_setprio(1);
#pragma unroll
        for (int j = 0; j < 8; ++j) {
            int row = j * 16 + l15;                    // row&7 == l15&7
            const u16* kr = kb + (size_t)row * 64;
            short8 k0 = *(const short8*)(kr + ((quad ^ (l15 & 7)) * 8));
            short8 k1 = *(const short8*)(kr + (((quad + 4) ^ (l15 & 7)) * 8));
            floatx4 a = {};
            a = __builtin_amdgcn_mfma_f32_16x16x32_bf16(k0, qf0, a, 0, 0, 0);
            a = __builtin_amdgcn_mfma_f32_16x16x32_bf16(k1, qf1, a, 0, 0, 0);
            s[j] = a;
        }
        __builtin_amdgcn_s_setprio(0);

        // --- per-32-kv chunk: p = exp2(s), pack+store P, then PV on that chunk ---
        const u16* vb = Vt[it & 1];
#pragma unroll
        for (int kh = 0; kh < 4; ++kh) {
            // produce P chunk kh (kv = kh*32 .. kh*32+31), q = l15
#pragma unroll
            for (int t = 0; t < 2; ++t) {
                int j = kh * 2 + t;
                float p0 = exp2f(s[j][0]), p1 = exp2f(s[j][1]);
                float p2 = exp2f(s[j][2]), p3 = exp2f(s[j][3]);
                u32 w0 = cvtpk(p0, p1), w1 = cvtpk(p2, p3);
                // kv' = t*16 + quad*4 + r  (4 contiguous bf16 -> one b64)
                *(u32x2*)(&Pl[wave][l15 * PST2 + t * 16 + quad * 4]) = (u32x2){w0, w1};
            }
            // consume: A-frag P[m=l15=q][k=quad*8+i]
            short8 pf = *(const short8*)(&Pl[wave][l15 * PST2 + quad * 8]);
            __builtin_amdgcn_s_setprio(1);
#pragma unroll
            for (int dj = 0; dj < 4; ++dj) {
                int row = dj * 16 + l15;
                int cg  = kh * 4 + quad;
                short8 vf = *(const short8*)(&vb[(row * 16 + (cg ^ l15)) * 8]);
                o[dj] = __builtin_amdgcn_mfma_f32_16x16x32_bf16(pf, vf, o[dj], 0, 0, 0);
            }
            // row-sum via ones B-frag: o_sum[r] += sum_k P[q=quad*4+r][k]
            o_sum = __builtin_amdgcn_mfma_f32_16x16x32_bf16(pf, onesf, o_sum, 0, 0, 0);
            __builtin_amdgcn_s_setprio(0);
        }
    }

    // --- epilogue: o_sum[r] is the full row sum for q=quad*4+r (all lanes) ---
#pragma unroll
    for (int r = 0; r < 4; ++r) {
        float invq = 1.f / o_sum[r];
        int srow = q0 + quad * 4 + r;
        size_t base = ((size_t)b * SEQ + srow) * D_MODEL + h * HDIM;
#pragma unroll
        for (int dj = 0; dj < 4; ++dj)
            O[base + dj * 16 + l15] = f2bf(o[dj][r] * invq);
    }
}

// ---------------------------------------------------------------------------
extern "C" void kernel_launch(void* const* d_in, const int* in_sizes, int n_in,
                              void* d_out, int out_size, void* d_ws, size_t ws_size,
                              hipStream_t stream) {
    const float* x  = (const float*)d_in[0];
    const float* Wq = (const float*)d_in[1];
    const float* bq = (const float*)d_in[2];
    const float* Wk = (const float*)d_in[3];
    const float* bk = (const float*)d_in[4];
    const float* Wv = (const float*)d_in[5];
    const float* bv = (const float*)d_in[6];
    const float* Wo = (const float*)d_in[7];
    const float* bo = (const float*)d_in[8];
    float* out = (float*)d_out;

    char* ws = (char*)d_ws;
    const size_t WSZ = (size_t)1024 * 1024 * sizeof(u16);   // 2MB per bf16 weight
    const size_t QSZ = (size_t)M_TOK * 1024 * sizeof(u16);  // 8MB per bf16 activation
    const size_t NEED = 4 * WSZ + 4 * QSZ;                  // 40MB

    if (ws_size < NEED) {
        zerofill_k<<<dim3((out_size + 255) / 256), 256, 0, stream>>>(out, out_size);
        return;
    }

    u16* wtq = (u16*)(ws);                       // wt q,k,v,o contiguous
    u16* wto = (u16*)(ws + 3 * WSZ);
    u16* Qw  = (u16*)(ws + 4 * WSZ);             // Q,K [B,H,S,64]; V^T [B,H,64,S]
    u16* Kw  = (u16*)(ws + 4 * WSZ + QSZ);
    u16* Vw  = (u16*)(ws + 4 * WSZ + 2 * QSZ);
    u16* Xb  = (u16*)(ws + 4 * WSZ + 3 * QSZ);   // x bf16; dead after gemm_qkv
    u16* Aw  = Xb;                               // attention output reuses Xb

    prep_k<<<dim3(32, 32, 5), 256, 0, stream>>>(x, Wq, Wk, Wv, Wo, wtq, Xb);

    gemm_qkv<<<dim3(8, 32, 3), 256, 0, stream>>>(Xb, wtq, bq, bk, bv, Qw);
    attn_k<<<dim3(SEQ / 128, BATCH * NHEADS), 512, 0, stream>>>(Qw, Kw, Vw, Aw);
    gemm_out<<<dim3(8, 64), 256, 0, stream>>>(Aw, wto, bo, out);
}

// Round 13
// 193.112 us; speedup vs baseline: 1.0246x; 1.0010x over previous
//
#include <hip/hip_runtime.h>

// Problem constants
#define D_MODEL 1024
#define NHEADS  16
#define HDIM    64
#define BATCH   2
#define SEQ     2048
#define M_TOK   (BATCH * SEQ)   // 4096

typedef unsigned short u16;
typedef unsigned int   u32;
typedef __attribute__((ext_vector_type(8))) short  short8;
typedef __attribute__((ext_vector_type(4))) float  floatx4;
typedef __attribute__((ext_vector_type(2))) u32    u32x2;

#define GLOBAL_AS __attribute__((address_space(1)))
#define LDS_AS    __attribute__((address_space(3)))

// async global->LDS, 16B per lane; LDS dst = wave-uniform base + lane*16 (m97 pattern)
static __device__ __forceinline__ void gload_lds16(const u16* g, u16* l) {
    __builtin_amdgcn_global_load_lds((const GLOBAL_AS u32*)g, (LDS_AS u32*)l, 16, 0, 0);
}

static __device__ __forceinline__ u16 f2bf(float f) {
    union { float f; u32 i; } v; v.f = f;
    u32 x = v.i;
    return (u16)((x + 0x7fffu + ((x >> 16) & 1u)) >> 16);
}

// pack 2 f32 -> 2 bf16 in one u32 (lo=a, hi=b), single VALU op
static __device__ __forceinline__ u32 cvtpk(float a, float b) {
    u32 r;
    asm("v_cvt_pk_bf16_f32 %0, %1, %2" : "=v"(r) : "v"(a), "v"(b));
    return r;
}

// load 8 fp32, RNE to bf16, pack as short8
static __device__ __forceinline__ short8 ld8_cvt(const float* __restrict__ p) {
    float4 f0 = *(const float4*)(p);
    float4 f1 = *(const float4*)(p + 4);
    short8 r;
    r[0] = (short)f2bf(f0.x); r[1] = (short)f2bf(f0.y);
    r[2] = (short)f2bf(f0.z); r[3] = (short)f2bf(f0.w);
    r[4] = (short)f2bf(f1.x); r[5] = (short)f2bf(f1.y);
    r[6] = (short)f2bf(f1.z); r[7] = (short)f2bf(f1.w);
    return r;
}

// ---------------------------------------------------------------------------
__global__ __launch_bounds__(256) void zerofill_k(float* __restrict__ out, int n) {
    int i = blockIdx.x * 256 + threadIdx.x;
    if (i < n) out[i] = 0.f;
}

// Fused prep, VECTORIZED. grid (32, 32, 5), block 256.
// z<4: 32x32 weight tile transpose: float4 loads -> LDS u16 [32][34] -> short8
//      stores. z==4: 16 floats/thread, 2x short8 stores.
__global__ __launch_bounds__(256) void prep_k(const float* __restrict__ x,
                                              const float* __restrict__ W0,
                                              const float* __restrict__ W1,
                                              const float* __restrict__ W2,
                                              const float* __restrict__ W3,
                                              u16* __restrict__ WtBase,
                                              u16* __restrict__ Xb) {
    int z = blockIdx.z;
    int t = threadIdx.x;
    if (z == 4) {
        int blk = blockIdx.y * 32 + blockIdx.x;          // 0..1023
        size_t i0 = ((size_t)blk * 256 + t) * 16;        // 16 floats/thread
        short8 v0 = ld8_cvt(x + i0);
        short8 v1 = ld8_cvt(x + i0 + 8);
        *(short8*)(Xb + i0)     = v0;
        *(short8*)(Xb + i0 + 8) = v1;
        return;
    }
    const float* W = (z == 0) ? W0 : (z == 1) ? W1 : (z == 2) ? W2 : W3;
    u16* Wt = WtBase + (size_t)z * 1024 * 1024;
    __shared__ u16 T[32][34];
    int bx = blockIdx.x * 32, by = blockIdx.y * 32;
    {
        int r = t >> 3, c4 = t & 7;                      // 32 rows x 8 float4
        float4 f = *(const float4*)(W + (size_t)(by + r) * 1024 + bx + c4 * 4);
        u32 lo = (u32)f2bf(f.x) | ((u32)f2bf(f.y) << 16);
        u32 hi = (u32)f2bf(f.z) | ((u32)f2bf(f.w) << 16);
        *(u32*)(&T[r][c4 * 4])     = lo;
        *(u32*)(&T[r][c4 * 4 + 2]) = hi;
    }
    __syncthreads();
    if (t < 128) {
        int n = t >> 2, seg = t & 3;                     // out row n, 8-k segment
        short8 v;
#pragma unroll
        for (int i = 0; i < 8; ++i) v[i] = (short)T[seg * 8 + i][n];
        *(short8*)(Wt + (size_t)(bx + n) * 1024 + by + seg * 8) = v;
    }
}

// ---------------------------------------------------------------------------
// GEMM core v3 (R8/R10 config — best measured): attn-style double-buffered
// single-barrier loop. prologue stages tile 0; per iter: __syncthreads()
// (drains DMA issued one iter ago), issue DMA(k+1), compute tile k.
// qkv BK=32 (dbuf 32KB, linear staging); out BK=64 (dbuf 48KB, both-sides
// XOR swizzle since 128B rows are bank-degenerate).
// MODE 0: C[row*1024+col] fp32(OUTF32) or bf16
// MODE 1: head-split [B,H,S,64] bf16
// MODE 2: head-split TRANSPOSED [B,H,64,S] bf16 (MI must be 4)
// ---------------------------------------------------------------------------
template <int MODE, int OUTF32, int MI, int BK>
static __device__ __forceinline__ void gemm_core(u16* __restrict__ smem,
                                                 const u16* __restrict__ A,
                                                 const u16* __restrict__ Bt,
                                                 const float* __restrict__ bias,
                                                 float scale,
                                                 void* __restrict__ C,
                                                 int m0, int n0) {
    constexpr int RG   = BK / 8;                 // granules per row
    constexpr int BUFG = (MI * 32 + 128) * RG;   // granules per buffer
    int tid  = threadIdx.x;
    int wave = tid >> 6, lane = tid & 63;
    int quad = lane >> 4, l15 = lane & 15;
    int wm = (wave & 1) * (MI * 16);
    int wn = (wave >> 1) * 64;

    // stage tile (k0) into buffer buf: A then B, linear LDS granules
    auto stage = [&](int buf, int k0) {
        u16* Asb = smem + (size_t)buf * BUFG * 8;
        u16* Bsb = Asb + MI * 32 * RG * 8;
#pragma unroll
        for (int t = 0; t < MI * 32 * RG / 256; ++t) {
            int a = t * 256 + tid;
            int row = a / RG, c = a & (RG - 1);
            int cs = (BK == 64) ? (c ^ (row & 7)) : c;
            gload_lds16(A + (size_t)(m0 + row) * 1024 + k0 + cs * 8,
                        Asb + (size_t)a * 8);
        }
#pragma unroll
        for (int t = 0; t < 128 * RG / 256; ++t) {
            int a = t * 256 + tid;
            int row = a / RG, c = a & (RG - 1);
            int cs = (BK == 64) ? (c ^ (row & 7)) : c;
            gload_lds16(Bt + (size_t)(n0 + row) * 1024 + k0 + cs * 8,
                        Bsb + (size_t)a * 8);
        }
    };

    floatx4 acc[MI][4] = {};
    stage(0, 0);

    for (int k0 = 0; k0 < 1024; k0 += BK) {
        int cur = (k0 / BK) & 1;
        __syncthreads();                 // DMA(cur) issued one iter ago: landed
        if (k0 + BK < 1024) stage(cur ^ 1, k0 + BK);

        u16* Asb = smem + (size_t)cur * BUFG * 8;
        u16* Bsb = Asb + MI * 32 * RG * 8;
#pragma unroll
        for (int h = 0; h < BK / 32; ++h) {
            short8 af[MI], bfr[4];
#pragma unroll
            for (int i = 0; i < MI; ++i) {
                int row = wm + i * 16 + l15;
                int g = (BK == 64) ? ((h * 4 + quad) ^ (l15 & 7)) : quad;
                af[i] = *(const short8*)(Asb + (size_t)row * BK + g * 8);
            }
#pragma unroll
            for (int j = 0; j < 4; ++j) {
                int row = wn + j * 16 + l15;
                int g = (BK == 64) ? ((h * 4 + quad) ^ (l15 & 7)) : quad;
                bfr[j] = *(const short8*)(Bsb + (size_t)row * BK + g * 8);
            }
#pragma unroll
            for (int i = 0; i < MI; ++i)
#pragma unroll
                for (int j = 0; j < 4; ++j)
                    acc[i][j] = __builtin_amdgcn_mfma_f32_16x16x32_bf16(af[i], bfr[j], acc[i][j], 0, 0, 0);
        }
    }

    if constexpr (MODE == 2) {
        // Transposed epilogue: two 64-col passes through LDS T[64][136], then
        // coalesced 256B row-bursts to V^T [B,H,64,S]. T aliases the buffers,
        // so sync before overwriting (loop no longer ends with one).
        __syncthreads();
        u16* T = smem;   // 64*136 u16
        int bb = m0 >> 11;
#pragma unroll
        for (int p = 0; p < 2; ++p) {
            if (p) __syncthreads();          // prior copy reads complete
            if ((wave >> 1) == p) {
#pragma unroll
                for (int j = 0; j < 4; ++j) {
                    int dcol = j * 16 + l15;                 // 0..63 within pass
                    float bv = bias[n0 + p * 64 + dcol];
#pragma unroll
                    for (int i = 0; i < MI; ++i) {
#pragma unroll
                        for (int rr = 0; rr < 2; ++rr) {
                            int srow = wm + i * 16 + quad * 4 + rr * 2;
                            u16 lo = f2bf((acc[i][j][rr * 2]     + bv) * scale);
                            u16 hi = f2bf((acc[i][j][rr * 2 + 1] + bv) * scale);
                            *(u32*)(T + dcol * 136 + srow) = (u32)lo | ((u32)hi << 16);
                        }
                    }
                }
            }
            __syncthreads();                 // T visible to all
            int d  = tid >> 2;               // 0..63
            int sc = (tid & 3) * 32;
            int col = n0 + p * 64 + d;
            int h = col >> 6, dd = col & 63;
            int s0 = (m0 & 2047) + sc;
            size_t gbase = (((size_t)bb * NHEADS + h) * HDIM + dd) * SEQ + s0;
#pragma unroll
            for (int c = 0; c < 4; ++c)
                *(short8*)((u16*)C + gbase + c * 8) = *(const short8*)(T + d * 136 + sc + c * 8);
        }
        return;
    }

    // epilogue (MODE 0/1): C/D layout col=lane&15, row=quad*4+reg
#pragma unroll
    for (int j = 0; j < 4; ++j) {
        int col = n0 + wn + j * 16 + l15;
        float bv = bias[col];
#pragma unroll
        for (int i = 0; i < MI; ++i) {
#pragma unroll
            for (int r = 0; r < 4; ++r) {
                int row = m0 + wm + i * 16 + quad * 4 + r;
                float v = (acc[i][j][r] + bv) * scale;
                size_t idx;
                if (MODE == 0) {
                    idx = (size_t)row * 1024 + col;
                } else {  // MODE 1: [B,H,S,64]
                    int b = row >> 11, s = row & 2047;
                    int h = col >> 6,  d = col & 63;
                    idx = (((size_t)b * NHEADS + h) * SEQ + s) * HDIM + d;
                }
                if constexpr (OUTF32) ((float*)C)[idx] = v;
                else                  ((u16*)C)[idx] = f2bf(v);
            }
        }
    }
}

// QKV fused: grid (8, 32, 3) = 768 blocks (3/CU), BK=32 dbuf (32KB x 3/CU).
// __launch_bounds__(256,3) pins VGPR<=170 (R5: -17us vs unpinned).
// R10 XCD swizzle: XCD x owns m-panels {4x..4x+3}; within XCD, n fastest,
// then z, then m -> A-panel fetched into one XCD L2, reused by 23 blocks.
__global__ __launch_bounds__(256, 3) void gemm_qkv(const u16* __restrict__ X,
                                                   const u16* __restrict__ WtBase,
                                                   const float* __restrict__ bq,
                                                   const float* __restrict__ bk,
                                                   const float* __restrict__ bv,
                                                   u16* __restrict__ OutBase) {
    __shared__ __align__(16) u16 smem[16384];   // 2 x (As 128x32 + Bs 128x32); T=8704 aliases
    int hw  = blockIdx.z * 256 + blockIdx.y * 8 + blockIdx.x;
    int x   = hw & 7;                // XCD (round-robin)
    int i   = hw >> 3;               // 0..95 within XCD
    int ml  = i / 24;                // 0..3
    int rem = i - ml * 24;
    int z   = rem >> 3;              // 0..2
    int n0  = (rem & 7) * 128;
    int m0  = (x * 4 + ml) * 128;
    const u16* Bt     = WtBase + (size_t)z * 1024 * 1024;
    const float* bias = (z == 0) ? bq : (z == 1) ? bk : bv;
    u16* C            = OutBase + (size_t)z * (size_t)M_TOK * 1024;
    if (z == 2)
        gemm_core<2, 0, 4, 32>(smem, X, Bt, bias, 1.0f, C, m0, n0);
    else if (z == 0)
        gemm_core<1, 0, 4, 32>(smem, X, Bt, bias, 0.18033688011112042f /* log2(e)/8 */, C, m0, n0);
    else
        gemm_core<1, 0, 4, 32>(smem, X, Bt, bias, 1.0f, C, m0, n0);
}

// Output projection: grid (8, 64) = 512 blocks (2/CU), BK=64 dbuf (48KB x 2).
// m-grouped XCD swizzle: XCD x owns m-tiles {8x..8x+7}; per-XCD working set
// A 1MB + B 2MB < 4MB L2. fp32 out.
__global__ __launch_bounds__(256, 2) void gemm_out(const u16* __restrict__ A,
                                                   const u16* __restrict__ Bt,
                                                   const float* __restrict__ bias,
                                                   float* __restrict__ C) {
    __shared__ __align__(16) u16 smem[24576];   // 2 x (As 64x64 + Bs 128x64)
    int hw = blockIdx.y * 8 + blockIdx.x;
    int x  = hw & 7;
    int i  = hw >> 3;                // 0..63
    int m0 = (x * 8 + (i >> 3)) * 64;
    int n0 = (i & 7) * 128;
    gemm_core<0, 1, 2, 64>(smem, A, Bt, bias, 1.0f, C, m0, n0);
}

// ---------------------------------------------------------------------------
// Flash attention v14 = v13 + INVARIANT-ADDRESS HOISTING.
// R12 post-mortem: head-swizzle cut FETCH 69.7->12.3MB, dur UNCHANGED ->
// not fetch-latency-bound. Highest-utilization pipe is VALU (52%), ~200 of
// ~370 VALU insts/wave-iter are ADDRESS RECOMPUTATION that is loop-invariant
// per lane (K/V frag XOR-swizzled LDS addrs, P round-trip) or constant-stride
// (DMA sources). m80/m97: hipcc does not hoist these.
// v14: unroll it-loop by 2 so the buffer index bi is COMPILE-TIME; precompute
// per-lane base pointers once; all LDS accesses become base_reg + constant
// offset: immediate (max 30720B < 64KB field). Identities used:
//   (quad+4)^s == (quad^s)^4           -> 2 K base pointers kb0/kb1
//   (kh*4+quad)^l15 == 4*(kh^(l15>>2)) | (quad^(l15&3))  -> 4 V ptrs vbs[kh]
// DMA sources advance by constant strides (+128 u16 V, +8192 u16 K).
// grid (SEQ/128, BATCH*NHEADS), 512 threads (8 waves), head-grouped swizzle.
// ---------------------------------------------------------------------------
#define PST2 40
__global__ __launch_bounds__(512, 3) void attn_k(const u16* __restrict__ Q,
                                                 const u16* __restrict__ K,
                                                 const u16* __restrict__ Vt_g,
                                                 u16* __restrict__ O) {
    __shared__ __align__(16) u16 Vt[2][64 * 128];   // V^T tile, swizzled granules, 2x16KB
    __shared__ __align__(16) u16 Kt[2][128 * 64];   // K tile, swizzled granules, 2x16KB
    __shared__ __align__(16) u16 Pl[8][16 * PST2];  // per-wave P chunk, 10240 B

    int tid  = threadIdx.x;
    int wave = tid >> 6, lane = tid & 63;
    int quad = lane >> 4, l15 = lane & 15;

    // head-grouped XCD swizzle: hw = y*16 + x (x fastest, round-robin XCD)
    int hw  = blockIdx.y * 16 + blockIdx.x;
    int xcd = hw & 7, i = hw >> 3;       // i in 0..63
    int bh  = xcd * 4 + (i >> 4);        // 4 heads per XCD
    int qb  = i & 15;                    // q-block within head

    int b = bh >> 4, h = bh & 15;
    const u16* Qb = Q    + (size_t)bh * SEQ * HDIM;
    const u16* Kb = K    + (size_t)bh * SEQ * HDIM;
    const u16* Vb = Vt_g + (size_t)bh * HDIM * SEQ;   // [d][s]
    int q0 = qb * 128 + wave * 16;

    // Q A/B-frags (pre-scaled): [m=l15][k=quad*8+j]
    short8 qf0 = *(const short8*)(Qb + (size_t)(q0 + l15) * 64 + quad * 8);
    short8 qf1 = *(const short8*)(Qb + (size_t)(q0 + l15) * 64 + 32 + quad * 8);

    // constant ones B-frag (bf16 1.0 = 0x3F80) for MFMA row-sums
    short8 onesf;
#pragma unroll
    for (int ii = 0; ii < 8; ++ii) onesf[ii] = (short)0x3F80;

    floatx4 o[4] = {};
    floatx4 o_sum = {};

    // --- precomputed per-lane LDS base pointers (loop-invariant) ---
    int s7 = l15 & 7;
    const u16* kb0 = &Kt[0][l15 * 64 + (quad ^ s7) * 8];          // + bi*8192 + j*1024
    const u16* kb1 = &Kt[0][l15 * 64 + ((quad ^ s7) ^ 4) * 8];
    const u16* vbs[4];
#pragma unroll
    for (int kh = 0; kh < 4; ++kh)
        vbs[kh] = &Vt[0][l15 * 128 + ((kh * 4 + quad) ^ l15) * 8]; // + bi*8192 + dj*2048
    u16* pst       = &Pl[wave][l15 * PST2 + quad * 4];             // + t*16
    const u16* prd = &Pl[wave][l15 * PST2 + quad * 8];

    // DMA K+V tile 0 into buffer 0 (each 1024 granules / 512 threads = 2 rounds)
    {
#pragma unroll
        for (int rnd = 0; rnd < 2; ++rnd) {
            int g = rnd * 512 + tid;
            int vrow = g >> 4, vc = g & 15;
            gload_lds16(Vb + (size_t)vrow * SEQ + (vc ^ (vrow & 15)) * 8,
                        Vt[0] + (size_t)g * 8);
            int krow = g >> 3, kc = g & 7;
            gload_lds16(Kb + (size_t)krow * 64 + (kc ^ (krow & 7)) * 8,
                        Kt[0] + (size_t)g * 8);
        }
    }

    // rolling DMA source pointers (tile 1 = kv 128), advance by const strides
    const u16* vsp[2];
    const u16* ksp[2];
#pragma unroll
    for (int rnd = 0; rnd < 2; ++rnd) {
        int g = rnd * 512 + tid;
        int vrow = g >> 4, vc = g & 15;
        vsp[rnd] = Vb + (size_t)vrow * SEQ + 128 + (vc ^ (vrow & 15)) * 8;
        int krow = g >> 3, kc = g & 7;
        ksp[rnd] = Kb + (size_t)(128 + krow) * 64 + (kc ^ (krow & 7)) * 8;
    }

    for (int i2 = 0; i2 < 8; ++i2) {
#pragma unroll
        for (int bi = 0; bi < 2; ++bi) {          // bi compile-time after unroll
            __syncthreads();   // drains DMA(it) [issued one iter ago]

            // --- issue K+V DMA(it+1) into buffer bi^1 ---
            if (i2 * 2 + bi < 15) {
#pragma unroll
                for (int rnd = 0; rnd < 2; ++rnd) {
                    int g = rnd * 512 + tid;
                    gload_lds16(vsp[rnd], Vt[bi ^ 1] + (size_t)g * 8);
                    gload_lds16(ksp[rnd], Kt[bi ^ 1] + (size_t)g * 8);
                    vsp[rnd] += 128;          // next kv-tile along s
                    ksp[rnd] += 128 * 64;     // next 128 rows
                }
            }

            // --- S^T = K @ Q^T, K frags at base + constant offsets ---
            floatx4 s[8];
            __builtin_amdgcn_s_setprio(1);
#pragma unroll
            for (int j = 0; j < 8; ++j) {
                short8 k0 = *(const short8*)(kb0 + bi * 8192 + j * 1024);
                short8 k1 = *(const short8*)(kb1 + bi * 8192 + j * 1024);
                floatx4 a = {};
                a = __builtin_amdgcn_mfma_f32_16x16x32_bf16(k0, qf0, a, 0, 0, 0);
                a = __builtin_amdgcn_mfma_f32_16x16x32_bf16(k1, qf1, a, 0, 0, 0);
                s[j] = a;
            }
            __builtin_amdgcn_s_setprio(0);

            // --- per-32-kv chunk: exp2 -> pack -> P -> PV ---
#pragma unroll
            for (int kh = 0; kh < 4; ++kh) {
#pragma unroll
                for (int t = 0; t < 2; ++t) {
                    int j = kh * 2 + t;
                    float p0 = exp2f(s[j][0]), p1 = exp2f(s[j][1]);
                    float p2 = exp2f(s[j][2]), p3 = exp2f(s[j][3]);
                    u32 w0 = cvtpk(p0, p1), w1 = cvtpk(p2, p3);
                    *(u32x2*)(pst + t * 16) = (u32x2){w0, w1};
                }
                short8 pf = *(const short8*)(prd);
                __builtin_amdgcn_s_setprio(1);
#pragma unroll
                for (int dj = 0; dj < 4; ++dj) {
                    short8 vf = *(const short8*)(vbs[kh] + bi * 8192 + dj * 2048);
                    o[dj] = __builtin_amdgcn_mfma_f32_16x16x32_bf16(pf, vf, o[dj], 0, 0, 0);
                }
                o_sum = __builtin_amdgcn_mfma_f32_16x16x32_bf16(pf, onesf, o_sum, 0, 0, 0);
                __builtin_amdgcn_s_setprio(0);
            }
        }
    }

    // --- epilogue: o_sum[r] is the full row sum for q=quad*4+r (all lanes) ---
#pragma unroll
    for (int r = 0; r < 4; ++r) {
        float invq = 1.f / o_sum[r];
        int srow = q0 + quad * 4 + r;
        size_t base = ((size_t)b * SEQ + srow) * D_MODEL + h * HDIM;
#pragma unroll
        for (int dj = 0; dj < 4; ++dj)
            O[base + dj * 16 + l15] = f2bf(o[dj][r] * invq);
    }
}

// ---------------------------------------------------------------------------
extern "C" void kernel_launch(void* const* d_in, const int* in_sizes, int n_in,
                              void* d_out, int out_size, void* d_ws, size_t ws_size,
                              hipStream_t stream) {
    const float* x  = (const float*)d_in[0];
    const float* Wq = (const float*)d_in[1];
    const float* bq = (const float*)d_in[2];
    const float* Wk = (const float*)d_in[3];
    const float* bk = (const float*)d_in[4];
    const float* Wv = (const float*)d_in[5];
    const float* bv = (const float*)d_in[6];
    const float* Wo = (const float*)d_in[7];
    const float* bo = (const float*)d_in[8];
    float* out = (float*)d_out;

    char* ws = (char*)d_ws;
    const size_t WSZ = (size_t)1024 * 1024 * sizeof(u16);   // 2MB per bf16 weight
    const size_t QSZ = (size_t)M_TOK * 1024 * sizeof(u16);  // 8MB per bf16 activation
    const size_t NEED = 4 * WSZ + 4 * QSZ;                  // 40MB

    if (ws_size < NEED) {
        zerofill_k<<<dim3((out_size + 255) / 256), 256, 0, stream>>>(out, out_size);
        return;
    }

    u16* wtq = (u16*)(ws);                       // wt q,k,v,o contiguous
    u16* wto = (u16*)(ws + 3 * WSZ);
    u16* Qw  = (u16*)(ws + 4 * WSZ);             // Q,K [B,H,S,64]; V^T [B,H,64,S]
    u16* Kw  = (u16*)(ws + 4 * WSZ + QSZ);
    u16* Vw  = (u16*)(ws + 4 * WSZ + 2 * QSZ);
    u16* Xb  = (u16*)(ws + 4 * WSZ + 3 * QSZ);   // x bf16; dead after gemm_qkv
    u16* Aw  = Xb;                               // attention output reuses Xb

    prep_k<<<dim3(32, 32, 5), 256, 0, stream>>>(x, Wq, Wk, Wv, Wo, wtq, Xb);

    gemm_qkv<<<dim3(8, 32, 3), 256, 0, stream>>>(Xb, wtq, bq, bk, bv, Qw);
    attn_k<<<dim3(SEQ / 128, BATCH * NHEADS), 512, 0, stream>>>(Qw, Kw, Vw, Aw);
    gemm_out<<<dim3(8, 64), 256, 0, stream>>>(Aw, wto, bo, out);
}